// Round 5
// baseline (171.032 us; speedup 1.0000x reference)
//
#include <hip/hip_runtime.h>
#include <stdint.h>

#define N_TOK 8192
#define DIN   1024
#define DOUT  1024
#define NG    8
#define LSCALE 2.0f
#define WROWS (DOUT + 16)   // W^T rows + appended WA^T rows

typedef __attribute__((ext_vector_type(4))) float  float4v;
typedef __attribute__((ext_vector_type(8))) short  short8;
typedef short8  frag_ab;   // 8 bf16
typedef float4v frag_cd;   // 4 fp32

__device__ __forceinline__ short f2bf(float f) {
    union { float f; uint32_t u; } v; v.f = f;
    uint32_t r = v.u + 0x7fffu + ((v.u >> 16) & 1u);  // RNE
    return (short)(r >> 16);
}

__device__ __forceinline__ void load_lds16(const void* g, void* lds) {
    __builtin_amdgcn_global_load_lds(
        (const __attribute__((address_space(1))) uint32_t*)g,
        (__attribute__((address_space(3))) uint32_t*)lds,
        16, 0, 0);
}

// ============ fused prep: cvt_x | W^T into WtA | WBt | WA^T into WtA | starts ============
#define PREP_GRID 6273

__global__ __launch_bounds__(256) void prep_kernel(
        const float* __restrict__ x, const float* __restrict__ Wb,
        const float* __restrict__ WA, const float* __restrict__ WB,
        const int* __restrict__ groups,
        short* __restrict__ xb, short* __restrict__ WtA,
        short* __restrict__ WBt, int* __restrict__ starts) {
    __shared__ float tile[64][65];
    const int blk = blockIdx.x, t = threadIdx.x;

    if (blk < 4096) {                       // ---- x fp32 -> bf16
        size_t idx = (size_t)(blk * 256 + t) * 8;
        const float4v* p = (const float4v*)(x + idx);
        float4v a = p[0], b = p[1];
        short8 o;
        o[0]=f2bf(a[0]); o[1]=f2bf(a[1]); o[2]=f2bf(a[2]); o[3]=f2bf(a[3]);
        o[4]=f2bf(b[0]); o[5]=f2bf(b[1]); o[6]=f2bf(b[2]); o[7]=f2bf(b[3]);
        *(short8*)(xb + idx) = o;
    } else if (blk < 6144) {                // ---- W_base [G][DIN][DOUT] -> WtA rows [0,1024)
        int b = blk - 4096;
        int g = b >> 8, rem = b & 255;
        int n0 = (rem & 15) * 64, k0 = (rem >> 4) * 64;
        const float* Wg = Wb + (size_t)g * DIN * DOUT;
#pragma unroll
        for (int i = 0; i < 4; ++i) {
            int idx = i * 256 + t;
            int r = idx >> 4, c = (idx & 15) * 4;
            float4v v = *(const float4v*)(Wg + (size_t)(k0 + r) * DOUT + n0 + c);
            tile[r][c+0]=v[0]; tile[r][c+1]=v[1]; tile[r][c+2]=v[2]; tile[r][c+3]=v[3];
        }
        __syncthreads();
        short* Wtg = WtA + (size_t)g * WROWS * DIN;
#pragma unroll
        for (int i = 0; i < 2; ++i) {
            int idx = i * 256 + t;
            int n = idx >> 3, c8 = (idx & 7) * 8;
            short8 o;
#pragma unroll
            for (int j = 0; j < 8; ++j) o[j] = f2bf(tile[c8 + j][n]);
            *(short8*)(Wtg + (size_t)(n0 + n) * DIN + k0 + c8) = o;
        }
    } else if (blk < 6176) {                // ---- W_B [G][16][DOUT] -> WBt [G][DOUT][32]
        int idx = (blk - 6144) * 256 + t;
        int g = idx >> 10, n = idx & 1023;
        const float* src = WB + (size_t)g * 16 * DOUT + n;
        short8 o0, o1;
#pragma unroll
        for (int r = 0; r < 8; ++r) o0[r] = f2bf(src[(size_t)r * DOUT]);
#pragma unroll
        for (int r = 0; r < 8; ++r) o1[r] = f2bf(src[(size_t)(r + 8) * DOUT]);
        short* dst = WBt + (size_t)idx * 32;
        *(short8*)dst        = o0;
        *(short8*)(dst + 8)  = o1;
        *(short8*)(dst + 16) = (short8)0;
        *(short8*)(dst + 24) = (short8)0;
    } else if (blk < 6240) {                // ---- W_A [G][DIN][16] -> WtA rows [1024,1040)
        int tid = (blk - 6176) * 256 + t;
        size_t o = (size_t)tid * 8;         // linear over [G][16][DIN]
        int g  = (int)(o >> 14);
        int rm = (int)(o & 16383);
        int r  = rm >> 10;
        int k0 = rm & 1023;
        const float* src = WA + (size_t)g * DIN * 16 + r;
        short8 ov;
#pragma unroll
        for (int j = 0; j < 8; ++j) ov[j] = f2bf(src[(size_t)(k0 + j) * 16]);
        *(short8*)(WtA + ((size_t)g * WROWS + DOUT + r) * DIN + k0) = ov;
    } else {                                // ---- starts from sorted groups
        int i = (blk - 6240) * 256 + t;
        if (i > N_TOK) return;
        int cur  = (i < N_TOK) ? groups[i] : NG;
        int prev = (i == 0) ? -1 : groups[i - 1];
        for (int g = prev + 1; g <= cur; ++g) starts[g] = i;
    }
}

// ============ fused grouped GEMM + LoRA: 128x64 tiles, 4 blocks/CU ============
#define BM 128
#define BN 64
#define BK 64
#define NKT (DIN / BK)

__global__ __launch_bounds__(256, 4)
void gemm_grouped(const short* __restrict__ xb,   // [N][DIN] bf16
                  const short* __restrict__ WtA,  // [G][1040][DIN] bf16 (W^T | WA^T)
                  const short* __restrict__ WBt,  // [G][DOUT][32] bf16 (k-padded)
                  const int*   __restrict__ starts,
                  float* __restrict__ out) {
    __shared__ short As[BM * BK];   // 16 KB
    __shared__ short Bs[BN * BK];   //  8 KB

    const int t    = threadIdx.x;
    const int lane = t & 63;
    const int wid  = t >> 6;
    // XCD-aware remap: xcd = L&7 owns rows [xcd*1024, +1024); within-XCD index m
    // sweeps 8 row-tiles fast, 16 col-tiles slow -> all 128 blocks of an XCD
    // co-resident (32 CU x 4 blocks) sharing A-band (2 MB) + W[g] (2 MB) in L2.
    const int L        = blockIdx.x;
    const int m        = L >> 3;                  // 0..127
    const int row_tile = (L & 7) * 8 + (m & 7);   // 0..63
    const int col_tile = m >> 3;                  // 0..15
    const int col0 = col_tile * BN;
    const int row0 = row_tile * BM;
    const int wr   = (wid >> 1) * 64;   // wave rows: 0 or 64
    const int wc   = (wid & 1) * 32;    // wave cols: 0 or 32
    const int m16  = lane & 15;
    const int q    = lane >> 4;
    const bool do_a = (wid & 1) == 0;   // waves 0,2 accumulate the lora-a column

    int gbeg = 0;
    while (starts[gbeg + 1] <= row0) ++gbeg;

    for (int g = gbeg; g < NG && starts[g] < row0 + BM; ++g) {
        const int rlo = starts[g]     > row0      ? starts[g]     : row0;
        const int rhi = starts[g + 1] < row0 + BM ? starts[g + 1] : row0 + BM;
        if (rlo >= rhi) continue;

        const short* wg = WtA + (size_t)g * WROWS * DIN;

        frag_cd acc[4][2];
        frag_cd acc_a[4];
#pragma unroll
        for (int i = 0; i < 4; ++i) {
#pragma unroll
            for (int j = 0; j < 2; ++j) { frag_cd z = {0.f,0.f,0.f,0.f}; acc[i][j] = z; }
            frag_cd z = {0.f,0.f,0.f,0.f}; acc_a[i] = z;
        }

        __syncthreads();   // protect LDS reuse across g iterations / a_lds alias

        for (int kt = 0; kt < DIN; kt += BK) {
            // stage A: x rows [row0,row0+128), XOR-swizzled 16B chunks
#pragma unroll
            for (int i = 0; i < 4; ++i) {
                int Lc = i * 256 + t;
                int r  = Lc >> 3;
                int c8 = (Lc & 7) ^ (r & 7);
                load_lds16(xb + (size_t)(row0 + r) * DIN + kt + c8 * 8,
                           &As[(i * 256 + wid * 64) * 8]);
            }
            // stage B: W^T rows [col0,col0+64)
#pragma unroll
            for (int i = 0; i < 2; ++i) {
                int Lc = i * 256 + t;
                int r  = Lc >> 3;
                int c8 = (Lc & 7) ^ (r & 7);
                load_lds16(wg + (size_t)(col0 + r) * DIN + kt + c8 * 8,
                           &Bs[(i * 256 + wid * 64) * 8]);
            }
            // lora-a B-fragments straight from global (L2-hot 32 KB slab)
            frag_ab ba0, ba1;
            if (do_a) {
                const short* tp = wg + (size_t)(DOUT + m16) * DIN + kt + q * 8;
                ba0 = *(const frag_ab*)tp;
                ba1 = *(const frag_ab*)(tp + 32);
            }
            __syncthreads();

#pragma unroll
            for (int kk = 0; kk < BK; kk += 32) {
                frag_ab af[4], bf[2];
                const int ch = (kk >> 3) + q;
#pragma unroll
                for (int mi = 0; mi < 4; ++mi) {
                    int rr = wr + mi * 16 + m16;
                    af[mi] = *(const frag_ab*)&As[rr * BK + ((ch ^ (rr & 7)) << 3)];
                }
#pragma unroll
                for (int ni = 0; ni < 2; ++ni) {
                    int cc = wc + ni * 16 + m16;
                    bf[ni] = *(const frag_ab*)&Bs[cc * BK + ((ch ^ (cc & 7)) << 3)];
                }
#pragma unroll
                for (int mi = 0; mi < 4; ++mi)
#pragma unroll
                    for (int ni = 0; ni < 2; ++ni)
                        acc[mi][ni] = __builtin_amdgcn_mfma_f32_16x16x32_bf16(
                            af[mi], bf[ni], acc[mi][ni], 0, 0, 0);
                if (do_a) {
                    frag_ab ba = kk ? ba1 : ba0;
#pragma unroll
                    for (int mi = 0; mi < 4; ++mi)
                        acc_a[mi] = __builtin_amdgcn_mfma_f32_16x16x32_bf16(
                            af[mi], ba, acc_a[mi], 0, 0, 0);
                }
            }
            __syncthreads();
        }

        // ---- LoRA epilogue: a (C-layout) -> LDS bf16 [128][40] -> A-frags x WB ----
        short* a_lds = As;   // 10240 B, safe after final barrier
        {   // zero pad cols [16,32) (cols [32,40) never read)
            int row = t >> 1, cz = 16 + (t & 1) * 8;
            *(short8*)&a_lds[row * 40 + cz] = (short8)0;
        }
        if (do_a) {
#pragma unroll
            for (int mi = 0; mi < 4; ++mi)
#pragma unroll
                for (int r = 0; r < 4; ++r) {
                    int row = wr + mi * 16 + q * 4 + r;
                    a_lds[row * 40 + m16] = f2bf(acc_a[mi][r] * LSCALE);
                }
        }
        __syncthreads();
        {
            frag_ab af[4], bfw[2];
#pragma unroll
            for (int mi = 0; mi < 4; ++mi)
                af[mi] = *(const frag_ab*)&a_lds[(wr + mi * 16 + m16) * 40 + q * 8];
#pragma unroll
            for (int ni = 0; ni < 2; ++ni)
                bfw[ni] = *(const frag_ab*)&WBt[((size_t)g * DOUT + col0 + wc + ni * 16 + m16) * 32 + q * 8];
#pragma unroll
            for (int mi = 0; mi < 4; ++mi)
#pragma unroll
                for (int ni = 0; ni < 2; ++ni)
                    acc[mi][ni] = __builtin_amdgcn_mfma_f32_16x16x32_bf16(
                        af[mi], bfw[ni], acc[mi][ni], 0, 0, 0);
        }

        // ---- masked store: C/D layout col = lane&15, row = q*4 + reg ----
#pragma unroll
        for (int mi = 0; mi < 4; ++mi)
#pragma unroll
            for (int r = 0; r < 4; ++r) {
                int grow = row0 + wr + mi * 16 + q * 4 + r;
                if (grow >= rlo && grow < rhi) {
                    float* orow = out + (size_t)grow * DOUT + col0 + wc + m16;
                    orow[0]  = acc[mi][0][r];
                    orow[16] = acc[mi][1][r];
                }
            }
    }
}

extern "C" void kernel_launch(void* const* d_in, const int* in_sizes, int n_in,
                              void* d_out, int out_size, void* d_ws, size_t ws_size,
                              hipStream_t stream) {
    const float* x      = (const float*)d_in[0];
    const int*   groups = (const int*)d_in[1];
    const float* Wb     = (const float*)d_in[2];
    const float* WA     = (const float*)d_in[3];
    const float* WB     = (const float*)d_in[4];
    float* out = (float*)d_out;

    char* ws = (char*)d_ws;
    int*   starts = (int*)ws;                                             // 36 B
    short* xb     = (short*)(ws + 1024);                                  // 16 MB
    short* WtA    = (short*)(ws + 1024 + (size_t)16 * 1024 * 1024);       // 16.25 MB
    short* WBt    = (short*)(ws + 1024 + (size_t)33 * 1024 * 1024);       // 512 KB

    hipLaunchKernelGGL(prep_kernel, dim3(PREP_GRID), dim3(256), 0, stream,
                       x, Wb, WA, WB, groups, xb, WtA, WBt, starts);
    hipLaunchKernelGGL(gemm_grouped, dim3(1024), dim3(256), 0, stream,
                       xb, WtA, WBt, starts, out);
}

// Round 7
// 148.816 us; speedup vs baseline: 1.1493x; 1.1493x over previous
//
#include <hip/hip_runtime.h>
#include <stdint.h>

#define N_TOK 8192
#define DIN   1024
#define DOUT  1024
#define NG    8
#define LSCALE 2.0f
#define WROWS (DOUT + 16)   // W^T rows + appended WA^T rows

typedef __attribute__((ext_vector_type(4))) float  float4v;
typedef __attribute__((ext_vector_type(8))) short  short8;
typedef short8  frag_ab;   // 8 bf16
typedef float4v frag_cd;   // 4 fp32

__device__ __forceinline__ short f2bf(float f) {
    union { float f; uint32_t u; } v; v.f = f;
    uint32_t r = v.u + 0x7fffu + ((v.u >> 16) & 1u);  // RNE
    return (short)(r >> 16);
}

__device__ __forceinline__ void load_lds16(const void* g, void* lds) {
    __builtin_amdgcn_global_load_lds(
        (const __attribute__((address_space(1))) uint32_t*)g,
        (__attribute__((address_space(3))) uint32_t*)lds,
        16, 0, 0);
}

// ============ fused prep: cvt_x | W^T into WtA | WBt | WA^T into WtA | starts ============
#define PREP_GRID 6273

__global__ __launch_bounds__(256) void prep_kernel(
        const float* __restrict__ x, const float* __restrict__ Wb,
        const float* __restrict__ WA, const float* __restrict__ WB,
        const int* __restrict__ groups,
        short* __restrict__ xb, short* __restrict__ WtA,
        short* __restrict__ WBt, int* __restrict__ starts) {
    __shared__ float tile[64][65];
    const int blk = blockIdx.x, t = threadIdx.x;

    if (blk < 4096) {                       // ---- x fp32 -> bf16
        size_t idx = (size_t)(blk * 256 + t) * 8;
        const float4v* p = (const float4v*)(x + idx);
        float4v a = p[0], b = p[1];
        short8 o;
        o[0]=f2bf(a[0]); o[1]=f2bf(a[1]); o[2]=f2bf(a[2]); o[3]=f2bf(a[3]);
        o[4]=f2bf(b[0]); o[5]=f2bf(b[1]); o[6]=f2bf(b[2]); o[7]=f2bf(b[3]);
        *(short8*)(xb + idx) = o;
    } else if (blk < 6144) {                // ---- W_base [G][DIN][DOUT] -> WtA rows [0,1024)
        int b = blk - 4096;
        int g = b >> 8, rem = b & 255;
        int n0 = (rem & 15) * 64, k0 = (rem >> 4) * 64;
        const float* Wg = Wb + (size_t)g * DIN * DOUT;
#pragma unroll
        for (int i = 0; i < 4; ++i) {
            int idx = i * 256 + t;
            int r = idx >> 4, c = (idx & 15) * 4;
            float4v v = *(const float4v*)(Wg + (size_t)(k0 + r) * DOUT + n0 + c);
            tile[r][c+0]=v[0]; tile[r][c+1]=v[1]; tile[r][c+2]=v[2]; tile[r][c+3]=v[3];
        }
        __syncthreads();
        short* Wtg = WtA + (size_t)g * WROWS * DIN;
#pragma unroll
        for (int i = 0; i < 2; ++i) {
            int idx = i * 256 + t;
            int n = idx >> 3, c8 = (idx & 7) * 8;
            short8 o;
#pragma unroll
            for (int j = 0; j < 8; ++j) o[j] = f2bf(tile[c8 + j][n]);
            *(short8*)(Wtg + (size_t)(n0 + n) * DIN + k0 + c8) = o;
        }
    } else if (blk < 6176) {                // ---- W_B [G][16][DOUT] -> WBt [G][DOUT][32]
        int idx = (blk - 6144) * 256 + t;
        int g = idx >> 10, n = idx & 1023;
        const float* src = WB + (size_t)g * 16 * DOUT + n;
        short8 o0, o1;
#pragma unroll
        for (int r = 0; r < 8; ++r) o0[r] = f2bf(src[(size_t)r * DOUT]);
#pragma unroll
        for (int r = 0; r < 8; ++r) o1[r] = f2bf(src[(size_t)(r + 8) * DOUT]);
        short* dst = WBt + (size_t)idx * 32;
        *(short8*)dst        = o0;
        *(short8*)(dst + 8)  = o1;
        *(short8*)(dst + 16) = (short8)0;
        *(short8*)(dst + 24) = (short8)0;
    } else if (blk < 6240) {                // ---- W_A [G][DIN][16] -> WtA rows [1024,1040)
        int tid = (blk - 6176) * 256 + t;
        size_t o = (size_t)tid * 8;         // linear over [G][16][DIN]
        int g  = (int)(o >> 14);
        int rm = (int)(o & 16383);
        int r  = rm >> 10;
        int k0 = rm & 1023;
        const float* src = WA + (size_t)g * DIN * 16 + r;
        short8 ov;
#pragma unroll
        for (int j = 0; j < 8; ++j) ov[j] = f2bf(src[(size_t)(k0 + j) * 16]);
        *(short8*)(WtA + ((size_t)g * WROWS + DOUT + r) * DIN + k0) = ov;
    } else {                                // ---- starts from sorted groups
        int i = (blk - 6240) * 256 + t;
        if (i > N_TOK) return;
        int cur  = (i < N_TOK) ? groups[i] : NG;
        int prev = (i == 0) ? -1 : groups[i - 1];
        for (int g = prev + 1; g <= cur; ++g) starts[g] = i;
    }
}

// ============ fused grouped GEMM + LoRA: 128x128 tiles, BK=128 (8 K-iters) ============
#define BM 128
#define BN 128
#define BK 128
#define NKT (DIN / BK)   // 8

__global__ __launch_bounds__(256, 2)
void gemm_grouped(const short* __restrict__ xb,   // [N][DIN] bf16
                  const short* __restrict__ WtA,  // [G][1040][DIN] bf16 (W^T | WA^T)
                  const short* __restrict__ WBt,  // [G][DOUT][32] bf16 (k-padded)
                  const int*   __restrict__ starts,
                  float* __restrict__ out) {
    __shared__ short As[BM * BK];   // 32 KB
    __shared__ short Bs[BN * BK];   // 32 KB  (total 64 KB -> 2 blocks/CU)

    const int t    = threadIdx.x;
    const int lane = t & 63;
    const int wid  = t >> 6;
    // XCD-aware remap (r3): xcd = L&7 owns rows [xcd*1024, +1024) x all col-tiles
    const int L        = blockIdx.x;
    const int row_tile = (L & 7) * 8 + (L >> 6);
    const int col_tile = (L >> 3) & 7;
    const int col0 = col_tile * BN;
    const int row0 = row_tile * BM;
    const int wr   = (wid >> 1) * 64;
    const int wc   = (wid & 1) * 64;
    const int m16  = lane & 15;
    const int q    = lane >> 4;
    const bool do_a = (wid & 1) == 0;       // waves 0,2 accumulate the lora-a column
    const int phase = ((L >> 3) & 1) * 4;   // stagger K-ring between co-resident blocks

    int gbeg = 0;
    while (starts[gbeg + 1] <= row0) ++gbeg;

    for (int g = gbeg; g < NG && starts[g] < row0 + BM; ++g) {
        const int rlo = starts[g]     > row0      ? starts[g]     : row0;
        const int rhi = starts[g + 1] < row0 + BM ? starts[g + 1] : row0 + BM;
        if (rlo >= rhi) continue;

        const short* wg = WtA + (size_t)g * WROWS * DIN;

        frag_cd acc[4][4];
        frag_cd acc_a[4];
#pragma unroll
        for (int i = 0; i < 4; ++i) {
#pragma unroll
            for (int j = 0; j < 4; ++j) { frag_cd z = {0.f,0.f,0.f,0.f}; acc[i][j] = z; }
            frag_cd z = {0.f,0.f,0.f,0.f}; acc_a[i] = z;
        }

        __syncthreads();   // protect LDS reuse across g iterations / a_lds alias

        for (int kt_ii = 0; kt_ii < NKT; ++kt_ii) {
            const int kt = ((kt_ii + phase) & (NKT - 1)) * BK;

            // stage A: 128 rows x 128 k. thread Lc -> LDS element Lc*8 (16 B/lane);
            // row r = Lc>>4 slot s = Lc&15 holds global chunk s ^ (r&7)
#pragma unroll
            for (int i = 0; i < 8; ++i) {
                int Lc = i * 256 + t;
                int r  = Lc >> 4;
                int c8 = (Lc & 15) ^ (r & 7);
                load_lds16(xb + (size_t)(row0 + r) * DIN + kt + c8 * 8,
                           &As[(i * 256 + wid * 64) * 8]);
            }
            // stage B: W^T rows [col0,col0+128) x 128 k
#pragma unroll
            for (int i = 0; i < 8; ++i) {
                int Lc = i * 256 + t;
                int r  = Lc >> 4;
                int c8 = (Lc & 15) ^ (r & 7);
                load_lds16(wg + (size_t)(col0 + r) * DIN + kt + c8 * 8,
                           &Bs[(i * 256 + wid * 64) * 8]);
            }
            // lora-a B-fragments straight from global (L2-hot 32 KB slab)
            frag_ab ba[4];
            if (do_a) {
                const short* tp = wg + (size_t)(DOUT + m16) * DIN + kt + q * 8;
#pragma unroll
                for (int j = 0; j < 4; ++j) ba[j] = *(const frag_ab*)(tp + j * 32);
            }
            __syncthreads();

#pragma unroll
            for (int kk = 0; kk < BK; kk += 32) {
                frag_ab af[4], bf[4];
                const int ch = (kk >> 3) + q;           // 0..15
#pragma unroll
                for (int mi = 0; mi < 4; ++mi) {
                    int rr = wr + mi * 16 + m16;
                    af[mi] = *(const frag_ab*)&As[rr * BK + ((ch ^ (rr & 7)) << 3)];
                }
#pragma unroll
                for (int ni = 0; ni < 4; ++ni) {
                    int cc = wc + ni * 16 + m16;
                    bf[ni] = *(const frag_ab*)&Bs[cc * BK + ((ch ^ (cc & 7)) << 3)];
                }
#pragma unroll
                for (int mi = 0; mi < 4; ++mi)
#pragma unroll
                    for (int ni = 0; ni < 4; ++ni)
                        acc[mi][ni] = __builtin_amdgcn_mfma_f32_16x16x32_bf16(
                            af[mi], bf[ni], acc[mi][ni], 0, 0, 0);
                if (do_a) {
#pragma unroll
                    for (int mi = 0; mi < 4; ++mi)
                        acc_a[mi] = __builtin_amdgcn_mfma_f32_16x16x32_bf16(
                            af[mi], ba[kk >> 5], acc_a[mi], 0, 0, 0);
                }
            }
            __syncthreads();
        }

        // ---- LoRA epilogue: a (C-layout) -> LDS bf16 [128][40] -> A-frags x WB ----
        short* a_lds = As;   // 10240 B, safe after final barrier
        {   // zero pad cols [16,32) (cols [32,40) never read)
            int row = t >> 1, cz = 16 + (t & 1) * 8;
            *(short8*)&a_lds[row * 40 + cz] = (short8)0;
        }
        if (do_a) {
#pragma unroll
            for (int mi = 0; mi < 4; ++mi)
#pragma unroll
                for (int r = 0; r < 4; ++r) {
                    int row = wr + mi * 16 + q * 4 + r;
                    a_lds[row * 40 + m16] = f2bf(acc_a[mi][r] * LSCALE);
                }
        }
        __syncthreads();
        {
            frag_ab af[4], bfw[4];
#pragma unroll
            for (int mi = 0; mi < 4; ++mi)
                af[mi] = *(const frag_ab*)&a_lds[(wr + mi * 16 + m16) * 40 + q * 8];
#pragma unroll
            for (int ni = 0; ni < 4; ++ni)
                bfw[ni] = *(const frag_ab*)&WBt[((size_t)g * DOUT + col0 + wc + ni * 16 + m16) * 32 + q * 8];
#pragma unroll
            for (int mi = 0; mi < 4; ++mi)
#pragma unroll
                for (int ni = 0; ni < 4; ++ni)
                    acc[mi][ni] = __builtin_amdgcn_mfma_f32_16x16x32_bf16(
                        af[mi], bfw[ni], acc[mi][ni], 0, 0, 0);
        }

        // ---- masked store: C/D layout col = lane&15, row = q*4 + reg ----
#pragma unroll
        for (int mi = 0; mi < 4; ++mi)
#pragma unroll
            for (int r = 0; r < 4; ++r) {
                int grow = row0 + wr + mi * 16 + q * 4 + r;
                if (grow >= rlo && grow < rhi) {
                    float* orow = out + (size_t)grow * DOUT + col0 + wc + m16;
#pragma unroll
                    for (int ni = 0; ni < 4; ++ni) orow[ni * 16] = acc[mi][ni][r];
                }
            }
    }
}

extern "C" void kernel_launch(void* const* d_in, const int* in_sizes, int n_in,
                              void* d_out, int out_size, void* d_ws, size_t ws_size,
                              hipStream_t stream) {
    const float* x      = (const float*)d_in[0];
    const int*   groups = (const int*)d_in[1];
    const float* Wb     = (const float*)d_in[2];
    const float* WA     = (const float*)d_in[3];
    const float* WB     = (const float*)d_in[4];
    float* out = (float*)d_out;

    char* ws = (char*)d_ws;
    int*   starts = (int*)ws;                                             // 36 B
    short* xb     = (short*)(ws + 1024);                                  // 16 MB
    short* WtA    = (short*)(ws + 1024 + (size_t)16 * 1024 * 1024);       // 16.25 MB
    short* WBt    = (short*)(ws + 1024 + (size_t)33 * 1024 * 1024);       // 512 KB

    hipLaunchKernelGGL(prep_kernel, dim3(PREP_GRID), dim3(256), 0, stream,
                       x, Wb, WA, WB, groups, xb, WtA, WBt, starts);
    hipLaunchKernelGGL(gemm_grouped, dim3(512), dim3(256), 0, stream,
                       xb, WtA, WBt, starts, out);
}